// Round 8
// baseline (51.670 us; speedup 1.0000x reference)
//
#include <hip/hip_runtime.h>
#include <math.h>
#include <stdint.h>

#define RESO 128
#define NUM_FEAT 16
#define DATA_DIM 16
#define MLP_W 128
#define NFREQ 4
#define BATCH 1024
#define NS 442
#define NT 256
#define NWAVES 4
#define STEPF ((float)(1.3 / 128.0))

// ---------------- Morton ----------------
static __device__ __forceinline__ uint32_t expand_bits(uint32_t v) {
    v = (v * 65537u) & 4278190335u;
    v = (v * 257u)   & 251719695u;
    v = (v * 17u)    & 3272356035u;
    v = (v * 5u)     & 1227133513u;
    return v;
}
static __device__ __forceinline__ uint32_t morton3d(uint32_t x, uint32_t y, uint32_t z) {
    return expand_bits(x) | (expand_bits(y) << 1) | (expand_bits(z) << 2);
}

// ------- Pre-pass: W1 data-part transpose -> [128][16] (tiny) -------
__global__ __launch_bounds__(128) void w1_prep_kernel(const float* __restrict__ W1,
                                                      float* __restrict__ W1dT) {
    int o = threadIdx.x;  // 0..127
#pragma unroll
    for (int j = 0; j < DATA_DIM; ++j) W1dT[o * DATA_DIM + j] = W1[j * MLP_W + o];
}

// gather + argmax + blend for one corner set, given cell base and offsets.
// Emits serial first-max-wins argmax (matches jnp.argmax), stores bi[8].
#define GATHER_BLEND(ixv, iyv, izv, oxv, oyv, ozv, XV, FRESH)                        \
    do {                                                                             \
        _Pragma("unroll")                                                            \
        for (int n = 0; n < 8; ++n) {                                                \
            int bx = (n >> 2) & 1, by = (n >> 1) & 1, bz = n & 1;                    \
            float wv = (bx ? (oxv) : 1.0f - (oxv)) * (by ? (oyv) : 1.0f - (oyv)) *   \
                       (bz ? (ozv) : 1.0f - (ozv));                                  \
            if (FRESH) {                                                             \
                int cx = min(max((ixv) + bx, 0), RESO - 1);                          \
                int cy = min(max((iyv) + by, 0), RESO - 1);                          \
                int cz = min(max((izv) + bz, 0), RESO - 1);                          \
                uint32_t mi = morton3d((uint32_t)cx, (uint32_t)cy, (uint32_t)cz);    \
                const float4* g4 = (const float4*)(grid + ((size_t)mi << 4));        \
                float4 A = g4[0], B = g4[1], C = g4[2], D = g4[3];                   \
                float v[16] = {A.x, A.y, A.z, A.w, B.x, B.y, B.z, B.w,               \
                               C.x, C.y, C.z, C.w, D.x, D.y, D.z, D.w};              \
                float bestv = v[0];                                                  \
                int bb = 0;                                                          \
                _Pragma("unroll")                                                    \
                for (int j = 1; j < 16; ++j) {                                       \
                    bb = (v[j] > bestv) ? j : bb;                                    \
                    bestv = fmaxf(v[j], bestv);                                      \
                }                                                                    \
                bi[n] = bb;                                                          \
            }                                                                        \
            const float4* cbr = (const float4*)&cbs[bi[n] * DATA_DIM];               \
            float4 ca = cbr[0], cb4 = cbr[1], cc = cbr[2], cd = cbr[3];              \
            XV[0]  = fmaf(wv, ca.x,  XV[0]);  XV[1]  = fmaf(wv, ca.y,  XV[1]);       \
            XV[2]  = fmaf(wv, ca.z,  XV[2]);  XV[3]  = fmaf(wv, ca.w,  XV[3]);       \
            XV[4]  = fmaf(wv, cb4.x, XV[4]);  XV[5]  = fmaf(wv, cb4.y, XV[5]);       \
            XV[6]  = fmaf(wv, cb4.z, XV[6]);  XV[7]  = fmaf(wv, cb4.w, XV[7]);       \
            XV[8]  = fmaf(wv, cc.x,  XV[8]);  XV[9]  = fmaf(wv, cc.y,  XV[9]);       \
            XV[10] = fmaf(wv, cc.z,  XV[10]); XV[11] = fmaf(wv, cc.w,  XV[11]);      \
            XV[12] = fmaf(wv, cd.x,  XV[12]); XV[13] = fmaf(wv, cd.y,  XV[13]);      \
            XV[14] = fmaf(wv, cd.z,  XV[14]); XV[15] = fmaf(wv, cd.w,  XV[15]);      \
        }                                                                            \
    } while (0)

// ------- Main: one block (256 thr, 4 waves) per ray; 2 samples/thread -------
__global__ __launch_bounds__(NT) void nerf_main_kernel(
    const float* __restrict__ rays_o, const float* __restrict__ rays_d,
    const float* __restrict__ grid, const float* __restrict__ cbg,
    const float* __restrict__ W1g, const float* __restrict__ b1g,
    const float* __restrict__ W2g, const float* __restrict__ b2g,
    const float* __restrict__ W1dT,
    float* __restrict__ out_rgb, float* __restrict__ out_alpha) {

    __shared__ __align__(16) float cbs[NUM_FEAT * DATA_DIM];
    __shared__ float pe_b1s[MLP_W];
    __shared__ float wtot[NWAVES];
    __shared__ float wred[NWAVES][4];

    const int b = blockIdx.x;
    const int t = threadIdx.x;
    const int wid = t >> 6;
    const int lane = t & 63;

    // per-ray setup (broadcast loads)
    const float o0 = rays_o[b * 3 + 0], o1 = rays_o[b * 3 + 1], o2 = rays_o[b * 3 + 2];
    const float d0 = rays_d[b * 3 + 0], d1 = rays_d[b * 3 + 1], d2 = rays_d[b * 3 + 2];
    const float R = 1.3f;
    float sd0 = (fabsf(d0) < 1e-8f) ? 1e-8f : d0;
    float sd1 = (fabsf(d1) < 1e-8f) ? 1e-8f : d1;
    float sd2 = (fabsf(d2) < 1e-8f) ? 1e-8f : d2;
    float ta0 = (-R - o0) / sd0, tb0 = (R - o0) / sd0;
    float ta1 = (-R - o1) / sd1, tb1 = (R - o1) / sd1;
    float ta2 = (-R - o2) / sd2, tb2 = (R - o2) / sd2;
    float tmin = fmaxf(fmaxf(fminf(ta0, tb0), fminf(ta1, tb1)), fminf(ta2, tb2));
    float tmax = fminf(fminf(fmaxf(ta0, tb0), fmaxf(ta1, tb1)), fmaxf(ta2, tb2));
    float tnear = fmaxf(tmin, 0.0f);
    float nrm = sqrtf(d0 * d0 + d1 * d1 + d2 * d2);

    cbs[t] = cbg[t];

    if (t < MLP_W) {
        float acc = b1g[t];
#pragma unroll
        for (int f = 0; f < NFREQ; ++f) {
            float fr = (float)(1 << f);
            acc = fmaf(__sinf(d0 * fr), W1g[(DATA_DIM + f * 6 + 0) * MLP_W + t], acc);
            acc = fmaf(__sinf(d1 * fr), W1g[(DATA_DIM + f * 6 + 1) * MLP_W + t], acc);
            acc = fmaf(__sinf(d2 * fr), W1g[(DATA_DIM + f * 6 + 2) * MLP_W + t], acc);
            acc = fmaf(__cosf(d0 * fr), W1g[(DATA_DIM + f * 6 + 3) * MLP_W + t], acc);
            acc = fmaf(__cosf(d1 * fr), W1g[(DATA_DIM + f * 6 + 4) * MLP_W + t], acc);
            acc = fmaf(__cosf(d2 * fr), W1g[(DATA_DIM + f * 6 + 5) * MLP_W + t], acc);
        }
        pe_b1s[t] = acc;
    }
    __syncthreads();

    // ---- two samples per thread: s0 = 2t, s1 = 2t+1 ----
    const int s0i = 2 * t;
    float tm0 = tnear + ((float)s0i + 0.5f) * STEPF;
    float tm1 = tm0 + STEPF;
    float delta = STEPF * nrm;

    float px0 = o0 + d0 * tm0, py0 = o1 + d1 * tm0, pz0 = o2 + d2 * tm0;
    float px1 = o0 + d0 * tm1, py1 = o1 + d1 * tm1, pz1 = o2 + d2 * tm1;
    bool valid = (s0i < NS);   // pairs are complete (NS even)
    bool m0 = valid && (tm0 < tmax) && (fabsf(px0) <= R) && (fabsf(py0) <= R) && (fabsf(pz0) <= R);
    bool m1 = valid && (tm1 < tmax) && (fabsf(px1) <= R) && (fabsf(py1) <= R) && (fabsf(pz1) <= R);

    float alpha0 = 0.0f, c00 = 0.0f, c01 = 0.0f, c02 = 0.0f;
    float alpha1 = 0.0f, c10 = 0.0f, c11 = 0.0f, c12 = 0.0f;

    float x0[DATA_DIM], x1[DATA_DIM];
#pragma unroll
    for (int j = 0; j < DATA_DIM; ++j) { x0[j] = 0.0f; x1[j] = 0.0f; }

    int bi[8];
    int cell0 = -1;

    if (m0) {
        float gx = (px0 / R + 1.0f) * (RESO * 0.5f);
        float gy = (py0 / R + 1.0f) * (RESO * 0.5f);
        float gz = (pz0 / R + 1.0f) * (RESO * 0.5f);
        float flx = floorf(gx), fly = floorf(gy), flz = floorf(gz);
        float ox = gx - flx, oy = gy - fly, oz = gz - flz;
        int ix = (int)flx, iy = (int)fly, iz = (int)flz;
        GATHER_BLEND(ix, iy, iz, ox, oy, oz, x0, true);
        cell0 = (ix * RESO + iy) * RESO + iz;
    }
    if (m1) {
        float gx = (px1 / R + 1.0f) * (RESO * 0.5f);
        float gy = (py1 / R + 1.0f) * (RESO * 0.5f);
        float gz = (pz1 / R + 1.0f) * (RESO * 0.5f);
        float flx = floorf(gx), fly = floorf(gy), flz = floorf(gz);
        float ox = gx - flx, oy = gy - fly, oz = gz - flz;
        int ix = (int)flx, iy = (int)fly, iz = (int)flz;
        int cell1 = (ix * RESO + iy) * RESO + iz;
        if (cell1 == cell0) {
            GATHER_BLEND(ix, iy, iz, ox, oy, oz, x1, false);   // reuse bi[] in-register
        } else {
            GATHER_BLEND(ix, iy, iz, ox, oy, oz, x1, true);
        }
    }

    // ---- MLP for both samples under one wave-uniform guard; weights via s_load,
    //      each W-row read amortized over 2 samples ----
    if (__any((int)(m0 | m1))) {
        float q0 = b2g[0], q1 = b2g[1], q2 = b2g[2], q3 = b2g[3];
        float p00 = q0, p01 = q1, p02 = q2, p03 = q3;
        float p10 = q0, p11 = q1, p12 = q2, p13 = q3;
#pragma unroll 2
        for (int o = 0; o < MLP_W; ++o) {
            float pb = pe_b1s[o];
            const float4* wr = (const float4*)(W1dT + o * DATA_DIM);  // uniform -> s_load
            float4 wa = wr[0], wb = wr[1], wc = wr[2], wd = wr[3];
            float a0 = pb, a1 = pb;
            a0 = fmaf(x0[0],  wa.x, a0);  a1 = fmaf(x1[0],  wa.x, a1);
            a0 = fmaf(x0[1],  wa.y, a0);  a1 = fmaf(x1[1],  wa.y, a1);
            a0 = fmaf(x0[2],  wa.z, a0);  a1 = fmaf(x1[2],  wa.z, a1);
            a0 = fmaf(x0[3],  wa.w, a0);  a1 = fmaf(x1[3],  wa.w, a1);
            a0 = fmaf(x0[4],  wb.x, a0);  a1 = fmaf(x1[4],  wb.x, a1);
            a0 = fmaf(x0[5],  wb.y, a0);  a1 = fmaf(x1[5],  wb.y, a1);
            a0 = fmaf(x0[6],  wb.z, a0);  a1 = fmaf(x1[6],  wb.z, a1);
            a0 = fmaf(x0[7],  wb.w, a0);  a1 = fmaf(x1[7],  wb.w, a1);
            a0 = fmaf(x0[8],  wc.x, a0);  a1 = fmaf(x1[8],  wc.x, a1);
            a0 = fmaf(x0[9],  wc.y, a0);  a1 = fmaf(x1[9],  wc.y, a1);
            a0 = fmaf(x0[10], wc.z, a0);  a1 = fmaf(x1[10], wc.z, a1);
            a0 = fmaf(x0[11], wc.w, a0);  a1 = fmaf(x1[11], wc.w, a1);
            a0 = fmaf(x0[12], wd.x, a0);  a1 = fmaf(x1[12], wd.x, a1);
            a0 = fmaf(x0[13], wd.y, a0);  a1 = fmaf(x1[13], wd.y, a1);
            a0 = fmaf(x0[14], wd.z, a0);  a1 = fmaf(x1[14], wd.z, a1);
            a0 = fmaf(x0[15], wd.w, a0);  a1 = fmaf(x1[15], wd.w, a1);
            float h0 = fmaxf(a0, 0.0f), h1 = fmaxf(a1, 0.0f);
            float4 w2 = *(const float4*)(W2g + o * 4);                // uniform -> s_load
            p00 = fmaf(h0, w2.x, p00);  p10 = fmaf(h1, w2.x, p10);
            p01 = fmaf(h0, w2.y, p01);  p11 = fmaf(h1, w2.y, p11);
            p02 = fmaf(h0, w2.z, p02);  p12 = fmaf(h1, w2.z, p12);
            p03 = fmaf(h0, w2.w, p03);  p13 = fmaf(h1, w2.w, p13);
        }
        if (m0) {
            float dens = fmaxf(p00, 0.0f);
            alpha0 = 1.0f - __expf(-dens * delta);
            c00 = 1.0f / (1.0f + __expf(-p01));
            c01 = 1.0f / (1.0f + __expf(-p02));
            c02 = 1.0f / (1.0f + __expf(-p03));
        }
        if (m1) {
            float dens = fmaxf(p10, 0.0f);
            alpha1 = 1.0f - __expf(-dens * delta);
            c10 = 1.0f / (1.0f + __expf(-p11));
            c11 = 1.0f / (1.0f + __expf(-p12));
            c12 = 1.0f / (1.0f + __expf(-p13));
        }
    }

    // ---- compositing: thread-local pair product, wave scan, cross-wave combine ----
    float e0 = 1.0f - alpha0 + 1e-10f;
    float e1 = 1.0f - alpha1 + 1e-10f;
    float tv = e0 * e1;
    float inc = tv;
#pragma unroll
    for (int off = 1; off < 64; off <<= 1) {
        float u = __shfl_up(inc, off, 64);
        if (lane >= off) inc *= u;
    }
    float excl = __shfl_up(inc, 1, 64);
    if (lane == 0) excl = 1.0f;
    if (lane == 63) wtot[wid] = inc;
    __syncthreads();

    float wpre = 1.0f;
#pragma unroll
    for (int w = 0; w < NWAVES; ++w)
        if (w < wid) wpre *= wtot[w];
    float T0 = wpre * excl;
    float T1 = T0 * e0;
    float w0 = alpha0 * T0, w1 = alpha1 * T1;
    float r0 = w0 * c00 + w1 * c10;
    float r1 = w0 * c01 + w1 * c11;
    float r2 = w0 * c02 + w1 * c12;
    float rw = w0 + w1;

    if (valid) {
        float2 st; st.x = alpha0; st.y = alpha1;
        ((float2*)(out_alpha + (size_t)b * NS))[t] = st;
    }

    // ---- final rgb reduction ----
#pragma unroll
    for (int off = 32; off >= 1; off >>= 1) {
        r0 += __shfl_down(r0, off, 64);
        r1 += __shfl_down(r1, off, 64);
        r2 += __shfl_down(r2, off, 64);
        rw += __shfl_down(rw, off, 64);
    }
    if (lane == 0) { wred[wid][0] = r0; wred[wid][1] = r1; wred[wid][2] = r2; wred[wid][3] = rw; }
    __syncthreads();
    if (t == 0) {
        float s0 = 0, s1 = 0, s2 = 0, sw = 0;
#pragma unroll
        for (int i = 0; i < NWAVES; ++i) {
            s0 += wred[i][0]; s1 += wred[i][1]; s2 += wred[i][2]; sw += wred[i][3];
        }
        float bg = 1.0f - sw;
        out_rgb[b * 3 + 0] = s0 + bg;
        out_rgb[b * 3 + 1] = s1 + bg;
        out_rgb[b * 3 + 2] = s2 + bg;
    }
}

extern "C" void kernel_launch(void* const* d_in, const int* in_sizes, int n_in,
                              void* d_out, int out_size, void* d_ws, size_t ws_size,
                              hipStream_t stream) {
    const float* rays_o   = (const float*)d_in[0];
    const float* rays_d   = (const float*)d_in[1];
    const float* grid     = (const float*)d_in[2];
    const float* codebook = (const float*)d_in[3];
    const float* W1       = (const float*)d_in[4];
    const float* b1       = (const float*)d_in[5];
    const float* W2       = (const float*)d_in[6];
    const float* b2       = (const float*)d_in[7];
    float* out = (float*)d_out;

    float* W1dT = (float*)d_ws;   // 128*16 f32 = 8 KB

    w1_prep_kernel<<<1, 128, 0, stream>>>(W1, W1dT);
    nerf_main_kernel<<<BATCH, NT, 0, stream>>>(
        rays_o, rays_d, grid, codebook, W1, b1, W2, b2, W1dT,
        out /* rgb: 1024*3 */, out + BATCH * 3 /* alpha: 1024*442 */);
}